// Round 16
// baseline (685.381 us; speedup 1.0000x reference)
//
#include <hip/hip_runtime.h>

typedef __bf16 bf16_t;
typedef __bf16 bf16x4 __attribute__((ext_vector_type(4)));
typedef __bf16 bf16x8 __attribute__((ext_vector_type(8)));
typedef float f32x4 __attribute__((ext_vector_type(4)));

#define QKV_SEG 33554432L  // elements per q/k/v segment: 2048 win * 8 heads * 64 tok * 32 d

#define GLDS(gp, lp)                                                                   \
  __builtin_amdgcn_global_load_lds((const __attribute__((address_space(1))) void*)(gp), \
                                   (__attribute__((address_space(3))) void*)(lp), 16, 0, 0)
#define BAR __builtin_amdgcn_s_barrier()
#define SCHED0 __builtin_amdgcn_sched_barrier(0)
#define MFMA __builtin_amdgcn_mfma_f32_16x16x32_bf16

// tanh-form GeLU: 0.5u(1+tanh(.7979(u+.044715u^3))) = u - u/(exp(2c)+1)
__device__ inline float gelu_f(float u) {
  float c2 = 1.5957691216057308f * (u + 0.044715f * u * u * u);
  return u - u / (__expf(c2) + 1.0f);
}

// ---------------- weight fp32 -> bf16 convert ----------------
__global__ __launch_bounds__(256) void cvt_kernel(const float* __restrict__ src,
                                                  bf16_t* __restrict__ dst) {
  int i = (blockIdx.x * 256 + threadIdx.x) * 4;
  float4 v = *(const float4*)(src + i);
  bf16x4 o;
  o[0] = (bf16_t)v.x; o[1] = (bf16_t)v.y; o[2] = (bf16_t)v.z; o[3] = (bf16_t)v.w;
  *(bf16x4*)(dst + i) = o;
}

// ---------------- LayerNorm1 + shift + window-partition gather ----------------
__global__ __launch_bounds__(256) void ln_kernel(const float* __restrict__ src,
                                                 const float* __restrict__ gw,
                                                 const float* __restrict__ gb,
                                                 bf16_t* __restrict__ dst) {
  int lane = threadIdx.x & 63, wv = threadIdx.x >> 6;
  long m = (long)blockIdx.x * 4 + wv;  // dest row (window-token order)
  long b_ = m >> 6; int tok = (int)(m & 63);
  int bb = (int)(b_ >> 8), win = (int)(b_ & 255);
  int wh = win >> 4, ww = win & 15;
  int ii = tok >> 3, jj = tok & 7;
  int hh = (wh * 8 + ii + 4) & 127, wp = (ww * 8 + jj + 4) & 127;
  long srow = ((long)bb << 14) + (hh << 7) + wp;

  float4 v = *(const float4*)(src + srow * 256 + lane * 4);
  float s = v.x + v.y + v.z + v.w;
  float s2 = v.x * v.x + v.y * v.y + v.z * v.z + v.w * v.w;
#pragma unroll
  for (int msk = 1; msk < 64; msk <<= 1) {
    s += __shfl_xor(s, msk);
    s2 += __shfl_xor(s2, msk);
  }
  float mean = s * (1.f / 256.f);
  float var = s2 * (1.f / 256.f) - mean * mean;
  float rs = rsqrtf(var + 1e-5f);
  float4 g4 = *(const float4*)(gw + lane * 4);
  float4 b4 = *(const float4*)(gb + lane * 4);
  bf16x4 o;
  o[0] = (bf16_t)((v.x - mean) * rs * g4.x + b4.x);
  o[1] = (bf16_t)((v.y - mean) * rs * g4.y + b4.y);
  o[2] = (bf16_t)((v.z - mean) * rs * g4.z + b4.z);
  o[3] = (bf16_t)((v.w - mean) * rs * g4.w + b4.w);
  *(bf16x4*)(dst + m * 256 + lane * 4) = o;
}

// ---------------- GEMM (QKV): BK=64 depth-2, counted vmcnt, XCD swizzle ----------------
__global__ __launch_bounds__(256) void gemm_kernel(const bf16_t* __restrict__ A,
                                                   const bf16_t* __restrict__ Bw,
                                                   const float* __restrict__ bias, int K,
                                                   bf16_t* __restrict__ out_bf) {
  __shared__ __align__(16) bf16_t As[2][8192];  // [buf][128*64]
  __shared__ __align__(16) bf16_t Bs[2][8192];
  int tid = threadIdx.x;
  int lane = tid & 63, wv = tid >> 6;
  int wm = wv >> 1, wn = wv & 1;

  int GX = gridDim.x, GY = gridDim.y;
  int flat = blockIdx.x + blockIdx.y * GX;
  int xcd = flat & 7, ii = flat >> 3;
  int iq = ii / GX;
  int by = xcd * (GY >> 3) + iq;
  int bx = ii - iq * GX;
  long m0 = (long)by * 128;
  int n0 = bx * 128;
  int lr = lane & 15, g = lane >> 4;

  int csw = (((lane & 7) ^ (lane >> 3)) << 3);
  const bf16_t* gA = A + (m0 + wv * 32 + (lane >> 3)) * K + csw;
  const bf16_t* gB = Bw + (long)(n0 + wv * 32 + (lane >> 3)) * K + csw;

  f32x4 acc[4][4] = {};

#define STAGE(buf, k0)                                                    \
  do {                                                                    \
    _Pragma("unroll") for (int s = 0; s < 4; ++s) {                       \
      GLDS(gA + (long)s * 8 * K + (k0), As[buf] + wv * 2048 + s * 512);   \
      GLDS(gB + (long)s * 8 * K + (k0), Bs[buf] + wv * 2048 + s * 512);   \
    }                                                                     \
  } while (0)

  int nt = K >> 6;
  STAGE(0, 0);
  for (int t = 0; t < nt; ++t) {
    int tb = t & 1;
    if (t + 1 < nt) {
      STAGE(tb ^ 1, (t + 1) << 6);
      asm volatile("s_waitcnt vmcnt(8)" ::: "memory");
    } else {
      asm volatile("s_waitcnt vmcnt(0)" ::: "memory");
    }
    BAR;
    SCHED0;
#pragma unroll
    for (int kk = 0; kk < 2; ++kk) {
      bf16x8 af[4], bfr[4];
#pragma unroll
      for (int mf = 0; mf < 4; ++mf)
        af[mf] = *(const bf16x8*)(As[tb] + (wm * 64 + mf * 16 + lr) * 64 +
                                  (((kk * 4 + g) ^ (lr & 7)) << 3));
#pragma unroll
      for (int nf = 0; nf < 4; ++nf)
        bfr[nf] = *(const bf16x8*)(Bs[tb] + (wn * 64 + nf * 16 + lr) * 64 +
                                   (((kk * 4 + g) ^ (lr & 7)) << 3));
#pragma unroll
      for (int mf = 0; mf < 4; ++mf)
#pragma unroll
        for (int nf = 0; nf < 4; ++nf)
          acc[mf][nf] = MFMA(af[mf], bfr[nf], acc[mf][nf], 0, 0, 0);
    }
    BAR;
  }
#undef STAGE

#pragma unroll
  for (int mf = 0; mf < 4; ++mf) {
#pragma unroll
    for (int nf = 0; nf < 4; ++nf) {
      long mb = m0 + wm * 64 + mf * 16 + 4 * g;
      int n = n0 + wn * 64 + nf * 16 + lr;
      float bn = bias[n];
      long b_ = mb >> 6;
      int tok = (int)(mb & 63);
      int which = n >> 8, rem = n & 255, head = rem >> 5, d = rem & 31;
      if (which == 2) {
        bf16x4 o;
#pragma unroll
        for (int r = 0; r < 4; ++r) o[r] = (bf16_t)(acc[mf][nf][r] + bn);
        *(bf16x4*)(out_bf + 2 * QKV_SEG + ((b_ * 8 + head) * 32 + d) * 64 + tok) = o;
      } else {
        long base = (long)which * QKV_SEG + ((b_ * 8 + head) * 64 + tok) * 32 + d;
#pragma unroll
        for (int r = 0; r < 4; ++r) out_bf[base + r * 32] = (bf16_t)(acc[mf][nf][r] + bn);
      }
    }
  }
}

// ---------------- fused attention + proj + reverse-shift residual ----------------
// One block per window (grid 2048), 4 waves. Attention as before, but O goes
// to LDS ao[64][264] instead of HBM (saves 134MB round-trip + a dispatch).
// Then per-wave 64tok x 64n proj (K=256) with wp from L2, R12-style batch
// prefetch; EPI1 epilogue: x1b[dst] = acc + proj_b + x[dst] (reverse shift).
__global__ __launch_bounds__(256) void attn2_kernel(const bf16_t* __restrict__ qkv,
                                                    const float* __restrict__ rpb,
                                                    const bf16_t* __restrict__ wp,
                                                    const float* __restrict__ proj_b,
                                                    const float* __restrict__ x,
                                                    bf16_t* __restrict__ x1b) {
  __shared__ float rpb_s[1800];       // 225 x 8
  __shared__ bf16_t P[4][64][72];     // +8 pad
  __shared__ bf16_t ao[64][264];      // attn output, +8 pad
  int tid = threadIdx.x, lane = tid & 63, wv = tid >> 6;
  long b_ = blockIdx.x;
  for (int i = tid; i < 1800; i += 256) rpb_s[i] = rpb[i];
  __syncthreads();
  const bf16_t* q = qkv;
  const bf16_t* k = qkv + QKV_SEG;
  const bf16_t* vt = qkv + 2 * QKV_SEG;
  int lr = lane & 15, lk = (lane >> 4) * 8, g = lane >> 4;
  const float scale = 0.17677669529663688f;  // 32^-0.5

  for (int hh = 0; hh < 2; ++hh) {
    int head = wv * 2 + hh;
    long base = (b_ * 8 + head) * 2048;
    bf16x8 af[4], bfr[4];
#pragma unroll
    for (int mf = 0; mf < 4; ++mf)
      af[mf] = *(const bf16x8*)(q + base + (mf * 16 + lr) * 32 + lk);
#pragma unroll
    for (int nf = 0; nf < 4; ++nf)
      bfr[nf] = *(const bf16x8*)(k + base + (nf * 16 + lr) * 32 + lk);
    f32x4 S[4][4] = {};
#pragma unroll
    for (int mf = 0; mf < 4; ++mf)
#pragma unroll
      for (int nf = 0; nf < 4; ++nf)
        S[mf][nf] = MFMA(af[mf], bfr[nf], S[mf][nf], 0, 0, 0);
#pragma unroll
    for (int mf = 0; mf < 4; ++mf)
#pragma unroll
      for (int nf = 0; nf < 4; ++nf)
#pragma unroll
        for (int r = 0; r < 4; ++r) {
          int i = mf * 16 + 4 * g + r, j = nf * 16 + lr;
          int rel = ((i >> 3) - (j >> 3) + 7) * 15 + ((i & 7) - (j & 7) + 7);
          S[mf][nf][r] = S[mf][nf][r] * scale + rpb_s[rel * 8 + head];
        }
#pragma unroll
    for (int mf = 0; mf < 4; ++mf) {
#pragma unroll
      for (int r = 0; r < 4; ++r) {
        float mx = fmaxf(fmaxf(S[mf][0][r], S[mf][1][r]), fmaxf(S[mf][2][r], S[mf][3][r]));
#pragma unroll
        for (int msk = 1; msk < 16; msk <<= 1) mx = fmaxf(mx, __shfl_xor(mx, msk));
        float sm = 0.f;
#pragma unroll
        for (int nf = 0; nf < 4; ++nf) {
          float e = __expf(S[mf][nf][r] - mx);
          S[mf][nf][r] = e;
          sm += e;
        }
#pragma unroll
        for (int msk = 1; msk < 16; msk <<= 1) sm += __shfl_xor(sm, msk);
        float is = 1.f / sm;
        int i = mf * 16 + 4 * g + r;
#pragma unroll
        for (int nf = 0; nf < 4; ++nf) P[wv][i][nf * 16 + lr] = (bf16_t)(S[mf][nf][r] * is);
      }
    }
    f32x4 O[4][2] = {};
#pragma unroll
    for (int ks = 0; ks < 2; ++ks) {
      int j0 = ks * 32;
      bf16x8 pa[4], vb[2];
#pragma unroll
      for (int mf = 0; mf < 4; ++mf) pa[mf] = *(const bf16x8*)(&P[wv][mf * 16 + lr][j0 + lk]);
#pragma unroll
      for (int nf = 0; nf < 2; ++nf)
        vb[nf] = *(const bf16x8*)(vt + base + (nf * 16 + lr) * 64 + j0 + lk);
#pragma unroll
      for (int mf = 0; mf < 4; ++mf)
#pragma unroll
        for (int nf = 0; nf < 2; ++nf)
          O[mf][nf] = MFMA(pa[mf], vb[nf], O[mf][nf], 0, 0, 0);
    }
#pragma unroll
    for (int mf = 0; mf < 4; ++mf)
#pragma unroll
      for (int nf = 0; nf < 2; ++nf)
#pragma unroll
        for (int r = 0; r < 4; ++r) {
          int i = mf * 16 + 4 * g + r, d = nf * 16 + lr;
          ao[i][head * 32 + d] = (bf16_t)O[mf][nf][r];
        }
  }
  __syncthreads();

  // ---- proj: wave wv computes 64 tok x n cols [wv*64, wv*64+64), K=256 ----
  f32x4 pacc[4][4] = {};
#pragma unroll
  for (int half = 0; half < 4; ++half) {  // 8 ksteps, 2 per batch
    bf16x8 bw[2][4];  // batch-issue 8 independent wp loads (R12-proven at 4 waves)
#pragma unroll
    for (int kb = 0; kb < 2; ++kb)
#pragma unroll
      for (int nf = 0; nf < 4; ++nf)
        bw[kb][nf] = *(const bf16x8*)(wp + (long)(wv * 64 + nf * 16 + lr) * 256 +
                                      (half * 2 + kb) * 32 + lk);
#pragma unroll
    for (int kb = 0; kb < 2; ++kb) {
      bf16x8 paf[4];
#pragma unroll
      for (int mf = 0; mf < 4; ++mf)
        paf[mf] = *(const bf16x8*)(&ao[mf * 16 + lr][(half * 2 + kb) * 32 + lk]);
#pragma unroll
      for (int mf = 0; mf < 4; ++mf)
#pragma unroll
        for (int nf = 0; nf < 4; ++nf)
          pacc[mf][nf] = MFMA(paf[mf], bw[kb][nf], pacc[mf][nf], 0, 0, 0);
    }
  }

  // ---- epilogue: reverse shift + residual(x fp32) -> x1b bf16 ----
  {
    int bb = (int)(b_ >> 8), win = (int)(b_ & 255);
    int wh = win >> 4, ww = win & 15;
#pragma unroll
    for (int mf = 0; mf < 4; ++mf)
#pragma unroll
      for (int nf = 0; nf < 4; ++nf) {
        int n = wv * 64 + nf * 16 + lr;
        float bn = proj_b[n];
#pragma unroll
        for (int r = 0; r < 4; ++r) {
          int tok = mf * 16 + 4 * g + r;
          int ii = tok >> 3, jj = tok & 7;
          int hh = (wh * 8 + ii + 4) & 127, wpp = (ww * 8 + jj + 4) & 127;
          long dst = (((long)bb << 14) + (hh << 7) + wpp) * 256 + n;
          x1b[dst] = (bf16_t)(pacc[mf][nf][r] + bn + x[dst]);
        }
      }
  }
}

// ---------------- fused MLP (R13-proven): LN2 + FC1 + GeLU + FC2 + residual ----------------
// 64 tok/block, 8 waves (512 thr), 51.2KB LDS -> 3 blocks/CU = 24 waves/CU.
__global__ __launch_bounds__(512, 6) void mlp_kernel(const bf16_t* __restrict__ x1b,
                                                     float* __restrict__ out,
                                                     const float* __restrict__ gw,
                                                     const float* __restrict__ gb,
                                                     const bf16_t* __restrict__ w1,
                                                     const float* __restrict__ b1,
                                                     const bf16_t* __restrict__ w2,
                                                     const float* __restrict__ b2) {
  __shared__ __align__(16) bf16_t ys[64][264];  // LN output (+8 pad)
  __shared__ __align__(16) bf16_t hs[64][136];  // h chunk [tok][hid128] (+8 pad)
  int tid = threadIdx.x, lane = tid & 63, wv = tid >> 6;  // wv in 0..7
  long m0 = (long)blockIdx.x * 64;
  int lr = lane & 15, lk = (lane >> 4) * 8, g = lane >> 4;

  // ---- LN2 (bf16 in): 8 rows per wave ----
  float4 g4 = *(const float4*)(gw + lane * 4);
  float4 b4 = *(const float4*)(gb + lane * 4);
#pragma unroll
  for (int i = 0; i < 8; ++i) {
    int r = wv * 8 + i;
    bf16x4 xv = *(const bf16x4*)(x1b + (m0 + r) * 256 + lane * 4);
    float v0 = (float)xv[0], v1 = (float)xv[1], v2 = (float)xv[2], v3 = (float)xv[3];
    float s = v0 + v1 + v2 + v3;
    float s2 = v0 * v0 + v1 * v1 + v2 * v2 + v3 * v3;
#pragma unroll
    for (int msk = 1; msk < 64; msk <<= 1) {
      s += __shfl_xor(s, msk);
      s2 += __shfl_xor(s2, msk);
    }
    float mean = s * (1.f / 256.f);
    float var = s2 * (1.f / 256.f) - mean * mean;
    float rs = rsqrtf(var + 1e-5f);
    bf16x4 o;
    o[0] = (bf16_t)((v0 - mean) * rs * g4.x + b4.x);
    o[1] = (bf16_t)((v1 - mean) * rs * g4.y + b4.y);
    o[2] = (bf16_t)((v2 - mean) * rs * g4.z + b4.z);
    o[3] = (bf16_t)((v3 - mean) * rs * g4.w + b4.w);
    *(bf16x4*)(&ys[r][lane * 4]) = o;
  }
  __syncthreads();

  f32x4 acc2[4][2] = {};  // FC2: 64 tok x 32 n per wave (n = wv*32..)

  for (int hc = 0; hc < 8; ++hc) {
    // ---- FC1' chunk: h^T[128 hid][64 tok]; wave owns 16 hid rows ----
    f32x4 acc1[4] = {};
#pragma unroll
    for (int half = 0; half < 2; ++half) {
      bf16x8 xf[4];  // batch-issue 4 independent w1 loads
#pragma unroll
      for (int kb = 0; kb < 4; ++kb)
        xf[kb] = *(const bf16x8*)(w1 + (long)(hc * 128 + wv * 16 + lr) * 256 +
                                  (half * 4 + kb) * 32 + lk);
#pragma unroll
      for (int kb = 0; kb < 4; ++kb) {
        bf16x8 yf[4];
#pragma unroll
        for (int nt = 0; nt < 4; ++nt)
          yf[nt] = *(const bf16x8*)(&ys[nt * 16 + lr][(half * 4 + kb) * 32 + lk]);
#pragma unroll
        for (int nt = 0; nt < 4; ++nt) acc1[nt] = MFMA(xf[kb], yf[nt], acc1[nt], 0, 0, 0);
      }
    }
    // bias + GeLU -> hs[tok][hid] (bf16x4, hidden-consecutive)
    {
      float4 bb = *(const float4*)(b1 + hc * 128 + wv * 16 + 4 * g);
#pragma unroll
      for (int nt = 0; nt < 4; ++nt) {
        bf16x4 o;
#pragma unroll
        for (int r = 0; r < 4; ++r) o[r] = (bf16_t)gelu_f(acc1[nt][r] + ((const float*)&bb)[r]);
        *(bf16x4*)(&hs[nt * 16 + lr][wv * 16 + 4 * g]) = o;
      }
    }
    __syncthreads();
    // ---- FC2 accumulate ----
#pragma unroll
    for (int half = 0; half < 2; ++half) {
      bf16x8 bw[2][2];
#pragma unroll
      for (int kb = 0; kb < 2; ++kb)
#pragma unroll
        for (int nf = 0; nf < 2; ++nf)
          bw[kb][nf] = *(const bf16x8*)(w2 + (long)(wv * 32 + nf * 16 + lr) * 1024 + hc * 128 +
                                        (half * 2 + kb) * 32 + lk);
#pragma unroll
      for (int kb = 0; kb < 2; ++kb) {
        bf16x8 ah[4];
#pragma unroll
        for (int mf = 0; mf < 4; ++mf)
          ah[mf] = *(const bf16x8*)(&hs[mf * 16 + lr][(half * 2 + kb) * 32 + lk]);
#pragma unroll
        for (int mf = 0; mf < 4; ++mf)
#pragma unroll
          for (int nf = 0; nf < 2; ++nf)
            acc2[mf][nf] = MFMA(ah[mf], bw[kb][nf], acc2[mf][nf], 0, 0, 0);
      }
    }
    __syncthreads();  // hs reads done before next chunk overwrites
  }

  // ---- epilogue: out = x1 + b2 + mlp (sole writer of d_out) ----
#pragma unroll
  for (int mf = 0; mf < 4; ++mf)
#pragma unroll
    for (int nf = 0; nf < 2; ++nf) {
      int n = wv * 32 + nf * 16 + lr;
      float bn = b2[n];
#pragma unroll
      for (int r = 0; r < 4; ++r) {
        long row = m0 + mf * 16 + 4 * g + r;
        out[row * 256 + n] = acc2[mf][nf][r] + bn + (float)x1b[row * 256 + n];
      }
    }
}

extern "C" void kernel_launch(void* const* d_in, const int* in_sizes, int n_in,
                              void* d_out, int out_size, void* d_ws, size_t ws_size,
                              hipStream_t stream) {
  const float* x = (const float*)d_in[0];
  const float* n1w = (const float*)d_in[1];
  const float* n1b = (const float*)d_in[2];
  const float* qkv_w = (const float*)d_in[3];
  const float* qkv_b = (const float*)d_in[4];
  const float* rpb = (const float*)d_in[5];
  const float* proj_w = (const float*)d_in[6];
  const float* proj_b = (const float*)d_in[7];
  const float* n2w = (const float*)d_in[8];
  const float* n2b = (const float*)d_in[9];
  const float* fc1_w = (const float*)d_in[10];
  const float* fc1_b = (const float*)d_in[11];
  const float* fc2_w = (const float*)d_in[12];
  const float* fc2_b = (const float*)d_in[13];
  float* out = (float*)d_out;

  char* ws = (char*)d_ws;
  bf16_t* bufA = (bf16_t*)ws;                       // qkv (201MB)
  bf16_t* x1b = (bf16_t*)(ws + 201326592L);         // x1 bf16 (67MB)
  bf16_t* bufB = (bf16_t*)(ws + 268435456L);        // xw (67MB)
  bf16_t* wq = (bf16_t*)(ws + 335544320L);          // bf16 weights (1.6MB)
  bf16_t* wp = wq + 196608;
  bf16_t* w1 = wp + 65536;
  bf16_t* w2 = w1 + 262144;

  // weights -> bf16
  cvt_kernel<<<192, 256, 0, stream>>>(qkv_w, wq);
  cvt_kernel<<<64, 256, 0, stream>>>(proj_w, wp);
  cvt_kernel<<<256, 256, 0, stream>>>(fc1_w, w1);
  cvt_kernel<<<256, 256, 0, stream>>>(fc2_w, w2);

  // LN1 + shift + window partition -> xw (bufB)
  ln_kernel<<<32768, 256, 0, stream>>>(x, n1w, n1b, bufB);
  // QKV GEMM -> q/k/v_t (bufA)
  gemm_kernel<<<dim3(6, 1024), 256, 0, stream>>>(bufB, wq, qkv_b, 256, bufA);
  // fused attention + proj + reverse shift + residual(x) -> x1 bf16
  attn2_kernel<<<2048, 256, 0, stream>>>(bufA, rpb, wp, proj_b, x, x1b);
  // fused LN2 + FC1 + GeLU + FC2 + residual -> d_out (fp32, sole writer)
  mlp_kernel<<<2048, 512, 0, stream>>>(x1b, out, n2w, n2b, w1, fc1_b, w2, fc2_b);
}

// Round 17
// 598.045 us; speedup vs baseline: 1.1460x; 1.1460x over previous
//
#include <hip/hip_runtime.h>

typedef __bf16 bf16_t;
typedef __bf16 bf16x4 __attribute__((ext_vector_type(4)));
typedef __bf16 bf16x8 __attribute__((ext_vector_type(8)));
typedef float f32x4 __attribute__((ext_vector_type(4)));

#define QKV_SEG 33554432L  // elements per q/k/v segment: 2048 win * 8 heads * 64 tok * 32 d

#define GLDS(gp, lp)                                                                   \
  __builtin_amdgcn_global_load_lds((const __attribute__((address_space(1))) void*)(gp), \
                                   (__attribute__((address_space(3))) void*)(lp), 16, 0, 0)
#define BAR __builtin_amdgcn_s_barrier()
#define SCHED0 __builtin_amdgcn_sched_barrier(0)
#define MFMA __builtin_amdgcn_mfma_f32_16x16x32_bf16

// tanh-form GeLU: 0.5u(1+tanh(.7979(u+.044715u^3))) = u - u/(exp(2c)+1)
__device__ inline float gelu_f(float u) {
  float c2 = 1.5957691216057308f * (u + 0.044715f * u * u * u);
  return u - u / (__expf(c2) + 1.0f);
}

// ---------------- all weights fp32 -> bf16, one dispatch ----------------
// segments: [0,192) qkv_w, [192,256) proj_w, [256,512) fc1_w, [512,768) fc2_w
__global__ __launch_bounds__(256) void cvt_all_kernel(const float* __restrict__ s0,
                                                      const float* __restrict__ s1,
                                                      const float* __restrict__ s2,
                                                      const float* __restrict__ s3,
                                                      bf16_t* __restrict__ d0,
                                                      bf16_t* __restrict__ d1,
                                                      bf16_t* __restrict__ d2,
                                                      bf16_t* __restrict__ d3) {
  int b = blockIdx.x;
  const float* src;
  bf16_t* dst;
  int base;
  if (b < 192)      { src = s0; dst = d0; base = b; }
  else if (b < 256) { src = s1; dst = d1; base = b - 192; }
  else if (b < 512) { src = s2; dst = d2; base = b - 256; }
  else              { src = s3; dst = d3; base = b - 512; }
  int i = (base * 256 + threadIdx.x) * 4;
  float4 v = *(const float4*)(src + i);
  bf16x4 o;
  o[0] = (bf16_t)v.x; o[1] = (bf16_t)v.y; o[2] = (bf16_t)v.z; o[3] = (bf16_t)v.w;
  *(bf16x4*)(dst + i) = o;
}

// ---------------- LayerNorm1 + shift + window-partition gather ----------------
__global__ __launch_bounds__(256) void ln_kernel(const float* __restrict__ src,
                                                 const float* __restrict__ gw,
                                                 const float* __restrict__ gb,
                                                 bf16_t* __restrict__ dst) {
  int lane = threadIdx.x & 63, wv = threadIdx.x >> 6;
  long m = (long)blockIdx.x * 4 + wv;  // dest row (window-token order)
  long b_ = m >> 6; int tok = (int)(m & 63);
  int bb = (int)(b_ >> 8), win = (int)(b_ & 255);
  int wh = win >> 4, ww = win & 15;
  int ii = tok >> 3, jj = tok & 7;
  int hh = (wh * 8 + ii + 4) & 127, wp = (ww * 8 + jj + 4) & 127;
  long srow = ((long)bb << 14) + (hh << 7) + wp;

  float4 v = *(const float4*)(src + srow * 256 + lane * 4);
  float s = v.x + v.y + v.z + v.w;
  float s2 = v.x * v.x + v.y * v.y + v.z * v.z + v.w * v.w;
#pragma unroll
  for (int msk = 1; msk < 64; msk <<= 1) {
    s += __shfl_xor(s, msk);
    s2 += __shfl_xor(s2, msk);
  }
  float mean = s * (1.f / 256.f);
  float var = s2 * (1.f / 256.f) - mean * mean;
  float rs = rsqrtf(var + 1e-5f);
  float4 g4 = *(const float4*)(gw + lane * 4);
  float4 b4 = *(const float4*)(gb + lane * 4);
  bf16x4 o;
  o[0] = (bf16_t)((v.x - mean) * rs * g4.x + b4.x);
  o[1] = (bf16_t)((v.y - mean) * rs * g4.y + b4.y);
  o[2] = (bf16_t)((v.z - mean) * rs * g4.z + b4.z);
  o[3] = (bf16_t)((v.w - mean) * rs * g4.w + b4.w);
  *(bf16x4*)(dst + m * 256 + lane * 4) = o;
}

// ---------------- GEMM (QKV / proj): BK=64 depth-2, counted vmcnt, XCD swizzle ----------------
// EPI 0: qkv scatter -> q/k/v_t bf16
// EPI 1: proj + reverse-shift + residual(x fp32) -> x1 bf16 (out_bf)
template <int EPI>
__global__ __launch_bounds__(256) void gemm_kernel(const bf16_t* __restrict__ A,
                                                   const bf16_t* __restrict__ Bw,
                                                   const float* __restrict__ bias, int K,
                                                   bf16_t* __restrict__ out_bf,
                                                   const float* resid) {
  __shared__ __align__(16) bf16_t As[2][8192];  // [buf][128*64]
  __shared__ __align__(16) bf16_t Bs[2][8192];
  int tid = threadIdx.x;
  int lane = tid & 63, wv = tid >> 6;
  int wm = wv >> 1, wn = wv & 1;

  int GX = gridDim.x, GY = gridDim.y;
  int flat = blockIdx.x + blockIdx.y * GX;
  int xcd = flat & 7, ii = flat >> 3;
  int iq = ii / GX;
  int by = xcd * (GY >> 3) + iq;
  int bx = ii - iq * GX;
  long m0 = (long)by * 128;
  int n0 = bx * 128;
  int lr = lane & 15, g = lane >> 4;

  int csw = (((lane & 7) ^ (lane >> 3)) << 3);
  const bf16_t* gA = A + (m0 + wv * 32 + (lane >> 3)) * K + csw;
  const bf16_t* gB = Bw + (long)(n0 + wv * 32 + (lane >> 3)) * K + csw;

  f32x4 acc[4][4] = {};

#define STAGE(buf, k0)                                                    \
  do {                                                                    \
    _Pragma("unroll") for (int s = 0; s < 4; ++s) {                       \
      GLDS(gA + (long)s * 8 * K + (k0), As[buf] + wv * 2048 + s * 512);   \
      GLDS(gB + (long)s * 8 * K + (k0), Bs[buf] + wv * 2048 + s * 512);   \
    }                                                                     \
  } while (0)

  int nt = K >> 6;
  STAGE(0, 0);
  for (int t = 0; t < nt; ++t) {
    int tb = t & 1;
    if (t + 1 < nt) {
      STAGE(tb ^ 1, (t + 1) << 6);
      asm volatile("s_waitcnt vmcnt(8)" ::: "memory");
    } else {
      asm volatile("s_waitcnt vmcnt(0)" ::: "memory");
    }
    BAR;
    SCHED0;
#pragma unroll
    for (int kk = 0; kk < 2; ++kk) {
      bf16x8 af[4], bfr[4];
#pragma unroll
      for (int mf = 0; mf < 4; ++mf)
        af[mf] = *(const bf16x8*)(As[tb] + (wm * 64 + mf * 16 + lr) * 64 +
                                  (((kk * 4 + g) ^ (lr & 7)) << 3));
#pragma unroll
      for (int nf = 0; nf < 4; ++nf)
        bfr[nf] = *(const bf16x8*)(Bs[tb] + (wn * 64 + nf * 16 + lr) * 64 +
                                   (((kk * 4 + g) ^ (lr & 7)) << 3));
#pragma unroll
      for (int mf = 0; mf < 4; ++mf)
#pragma unroll
        for (int nf = 0; nf < 4; ++nf)
          acc[mf][nf] = MFMA(af[mf], bfr[nf], acc[mf][nf], 0, 0, 0);
    }
    BAR;
  }
#undef STAGE

#pragma unroll
  for (int mf = 0; mf < 4; ++mf) {
#pragma unroll
    for (int nf = 0; nf < 4; ++nf) {
      long mb = m0 + wm * 64 + mf * 16 + 4 * g;
      int n = n0 + wn * 64 + nf * 16 + lr;
      float bn = bias[n];
      if (EPI == 0) {
        long b_ = mb >> 6;
        int tok = (int)(mb & 63);
        int which = n >> 8, rem = n & 255, head = rem >> 5, d = rem & 31;
        if (which == 2) {
          bf16x4 o;
#pragma unroll
          for (int r = 0; r < 4; ++r) o[r] = (bf16_t)(acc[mf][nf][r] + bn);
          *(bf16x4*)(out_bf + 2 * QKV_SEG + ((b_ * 8 + head) * 32 + d) * 64 + tok) = o;
        } else {
          long base = (long)which * QKV_SEG + ((b_ * 8 + head) * 64 + tok) * 32 + d;
#pragma unroll
          for (int r = 0; r < 4; ++r) out_bf[base + r * 32] = (bf16_t)(acc[mf][nf][r] + bn);
        }
      } else {
#pragma unroll
        for (int r = 0; r < 4; ++r) {
          long m = mb + r;
          long b_ = m >> 6; int tok = (int)(m & 63);
          int bb = (int)(b_ >> 8), win = (int)(b_ & 255);
          int wh = win >> 4, ww = win & 15;
          int jj0 = tok >> 3, jj = tok & 7;
          int hh = (wh * 8 + jj0 + 4) & 127, wp = (ww * 8 + jj + 4) & 127;
          long dst = (((long)bb << 14) + (hh << 7) + wp) * 256 + n;
          out_bf[dst] = (bf16_t)(acc[mf][nf][r] + bn + resid[dst]);
        }
      }
    }
  }
}

// ---------------- fused MLP (R13-proven): LN2 + FC1 + GeLU + FC2 + residual ----------------
// 64 tok/block, 8 waves (512 thr), 51.2KB LDS -> 3 blocks/CU = 24 waves/CU.
__global__ __launch_bounds__(512, 6) void mlp_kernel(const bf16_t* __restrict__ x1b,
                                                     float* __restrict__ out,
                                                     const float* __restrict__ gw,
                                                     const float* __restrict__ gb,
                                                     const bf16_t* __restrict__ w1,
                                                     const float* __restrict__ b1,
                                                     const bf16_t* __restrict__ w2,
                                                     const float* __restrict__ b2) {
  __shared__ __align__(16) bf16_t ys[64][264];  // LN output (+8 pad)
  __shared__ __align__(16) bf16_t hs[64][136];  // h chunk [tok][hid128] (+8 pad)
  int tid = threadIdx.x, lane = tid & 63, wv = tid >> 6;  // wv in 0..7
  long m0 = (long)blockIdx.x * 64;
  int lr = lane & 15, lk = (lane >> 4) * 8, g = lane >> 4;

  // ---- LN2 (bf16 in): 8 rows per wave ----
  float4 g4 = *(const float4*)(gw + lane * 4);
  float4 b4 = *(const float4*)(gb + lane * 4);
#pragma unroll
  for (int i = 0; i < 8; ++i) {
    int r = wv * 8 + i;
    bf16x4 xv = *(const bf16x4*)(x1b + (m0 + r) * 256 + lane * 4);
    float v0 = (float)xv[0], v1 = (float)xv[1], v2 = (float)xv[2], v3 = (float)xv[3];
    float s = v0 + v1 + v2 + v3;
    float s2 = v0 * v0 + v1 * v1 + v2 * v2 + v3 * v3;
#pragma unroll
    for (int msk = 1; msk < 64; msk <<= 1) {
      s += __shfl_xor(s, msk);
      s2 += __shfl_xor(s2, msk);
    }
    float mean = s * (1.f / 256.f);
    float var = s2 * (1.f / 256.f) - mean * mean;
    float rs = rsqrtf(var + 1e-5f);
    bf16x4 o;
    o[0] = (bf16_t)((v0 - mean) * rs * g4.x + b4.x);
    o[1] = (bf16_t)((v1 - mean) * rs * g4.y + b4.y);
    o[2] = (bf16_t)((v2 - mean) * rs * g4.z + b4.z);
    o[3] = (bf16_t)((v3 - mean) * rs * g4.w + b4.w);
    *(bf16x4*)(&ys[r][lane * 4]) = o;
  }
  __syncthreads();

  f32x4 acc2[4][2] = {};  // FC2: 64 tok x 32 n per wave (n = wv*32..)

  for (int hc = 0; hc < 8; ++hc) {
    // ---- FC1' chunk: h^T[128 hid][64 tok]; wave owns 16 hid rows ----
    f32x4 acc1[4] = {};
#pragma unroll
    for (int half = 0; half < 2; ++half) {
      bf16x8 xf[4];  // batch-issue 4 independent w1 loads
#pragma unroll
      for (int kb = 0; kb < 4; ++kb)
        xf[kb] = *(const bf16x8*)(w1 + (long)(hc * 128 + wv * 16 + lr) * 256 +
                                  (half * 4 + kb) * 32 + lk);
#pragma unroll
      for (int kb = 0; kb < 4; ++kb) {
        bf16x8 yf[4];
#pragma unroll
        for (int nt = 0; nt < 4; ++nt)
          yf[nt] = *(const bf16x8*)(&ys[nt * 16 + lr][(half * 4 + kb) * 32 + lk]);
#pragma unroll
        for (int nt = 0; nt < 4; ++nt) acc1[nt] = MFMA(xf[kb], yf[nt], acc1[nt], 0, 0, 0);
      }
    }
    // bias + GeLU -> hs[tok][hid] (bf16x4, hidden-consecutive)
    {
      float4 bb = *(const float4*)(b1 + hc * 128 + wv * 16 + 4 * g);
#pragma unroll
      for (int nt = 0; nt < 4; ++nt) {
        bf16x4 o;
#pragma unroll
        for (int r = 0; r < 4; ++r) o[r] = (bf16_t)gelu_f(acc1[nt][r] + ((const float*)&bb)[r]);
        *(bf16x4*)(&hs[nt * 16 + lr][wv * 16 + 4 * g]) = o;
      }
    }
    __syncthreads();
    // ---- FC2 accumulate: out[tok][n] += h[tok][k]*w2[n][k], k = this 128-chunk ----
#pragma unroll
    for (int half = 0; half < 2; ++half) {
      bf16x8 bw[2][2];
#pragma unroll
      for (int kb = 0; kb < 2; ++kb)
#pragma unroll
        for (int nf = 0; nf < 2; ++nf)
          bw[kb][nf] = *(const bf16x8*)(w2 + (long)(wv * 32 + nf * 16 + lr) * 1024 + hc * 128 +
                                        (half * 2 + kb) * 32 + lk);
#pragma unroll
      for (int kb = 0; kb < 2; ++kb) {
        bf16x8 ah[4];
#pragma unroll
        for (int mf = 0; mf < 4; ++mf)
          ah[mf] = *(const bf16x8*)(&hs[mf * 16 + lr][(half * 2 + kb) * 32 + lk]);
#pragma unroll
        for (int mf = 0; mf < 4; ++mf)
#pragma unroll
          for (int nf = 0; nf < 2; ++nf)
            acc2[mf][nf] = MFMA(ah[mf], bw[kb][nf], acc2[mf][nf], 0, 0, 0);
      }
    }
    __syncthreads();  // hs reads done before next chunk overwrites
  }

  // ---- epilogue: out = x1 + b2 + mlp (sole writer of d_out) ----
#pragma unroll
  for (int mf = 0; mf < 4; ++mf)
#pragma unroll
    for (int nf = 0; nf < 2; ++nf) {
      int n = wv * 32 + nf * 16 + lr;
      float bn = b2[n];
#pragma unroll
      for (int r = 0; r < 4; ++r) {
        long row = m0 + mf * 16 + 4 * g + r;
        out[row * 256 + n] = acc2[mf][nf][r] + bn + (float)x1b[row * 256 + n];
      }
    }
}

// ---------------- per-window attention: 4 waves x 2 heads ----------------
__global__ __launch_bounds__(256) void attn_kernel(const bf16_t* __restrict__ qkv,
                                                   const float* __restrict__ rpb,
                                                   bf16_t* __restrict__ attn_out) {
  __shared__ float rpb_s[1800];       // 225 x 8
  __shared__ bf16_t P[4][64][72];     // +8 pad
  int tid = threadIdx.x, lane = tid & 63, wv = tid >> 6;
  long b_ = blockIdx.x;
  for (int i = tid; i < 1800; i += 256) rpb_s[i] = rpb[i];
  __syncthreads();
  const bf16_t* q = qkv;
  const bf16_t* k = qkv + QKV_SEG;
  const bf16_t* vt = qkv + 2 * QKV_SEG;
  int lr = lane & 15, lk = (lane >> 4) * 8, g = lane >> 4;
  const float scale = 0.17677669529663688f;  // 32^-0.5

  for (int hh = 0; hh < 2; ++hh) {
    int head = wv * 2 + hh;
    long base = (b_ * 8 + head) * 2048;
    bf16x8 af[4], bfr[4];
#pragma unroll
    for (int mf = 0; mf < 4; ++mf)
      af[mf] = *(const bf16x8*)(q + base + (mf * 16 + lr) * 32 + lk);
#pragma unroll
    for (int nf = 0; nf < 4; ++nf)
      bfr[nf] = *(const bf16x8*)(k + base + (nf * 16 + lr) * 32 + lk);
    f32x4 S[4][4] = {};
#pragma unroll
    for (int mf = 0; mf < 4; ++mf)
#pragma unroll
      for (int nf = 0; nf < 4; ++nf)
        S[mf][nf] = MFMA(af[mf], bfr[nf], S[mf][nf], 0, 0, 0);
#pragma unroll
    for (int mf = 0; mf < 4; ++mf)
#pragma unroll
      for (int nf = 0; nf < 4; ++nf)
#pragma unroll
        for (int r = 0; r < 4; ++r) {
          int i = mf * 16 + 4 * g + r, j = nf * 16 + lr;
          int rel = ((i >> 3) - (j >> 3) + 7) * 15 + ((i & 7) - (j & 7) + 7);
          S[mf][nf][r] = S[mf][nf][r] * scale + rpb_s[rel * 8 + head];
        }
#pragma unroll
    for (int mf = 0; mf < 4; ++mf) {
#pragma unroll
      for (int r = 0; r < 4; ++r) {
        float mx = fmaxf(fmaxf(S[mf][0][r], S[mf][1][r]), fmaxf(S[mf][2][r], S[mf][3][r]));
#pragma unroll
        for (int msk = 1; msk < 16; msk <<= 1) mx = fmaxf(mx, __shfl_xor(mx, msk));
        float sm = 0.f;
#pragma unroll
        for (int nf = 0; nf < 4; ++nf) {
          float e = __expf(S[mf][nf][r] - mx);
          S[mf][nf][r] = e;
          sm += e;
        }
#pragma unroll
        for (int msk = 1; msk < 16; msk <<= 1) sm += __shfl_xor(sm, msk);
        float is = 1.f / sm;
        int i = mf * 16 + 4 * g + r;
#pragma unroll
        for (int nf = 0; nf < 4; ++nf) P[wv][i][nf * 16 + lr] = (bf16_t)(S[mf][nf][r] * is);
      }
    }
    f32x4 O[4][2] = {};
#pragma unroll
    for (int ks = 0; ks < 2; ++ks) {
      int j0 = ks * 32;
      bf16x8 pa[4], vb[2];
#pragma unroll
      for (int mf = 0; mf < 4; ++mf) pa[mf] = *(const bf16x8*)(&P[wv][mf * 16 + lr][j0 + lk]);
#pragma unroll
      for (int nf = 0; nf < 2; ++nf)
        vb[nf] = *(const bf16x8*)(vt + base + (nf * 16 + lr) * 64 + j0 + lk);
#pragma unroll
      for (int mf = 0; mf < 4; ++mf)
#pragma unroll
        for (int nf = 0; nf < 2; ++nf)
          O[mf][nf] = MFMA(pa[mf], vb[nf], O[mf][nf], 0, 0, 0);
    }
#pragma unroll
    for (int mf = 0; mf < 4; ++mf)
#pragma unroll
      for (int nf = 0; nf < 2; ++nf)
#pragma unroll
        for (int r = 0; r < 4; ++r) {
          int i = mf * 16 + 4 * g + r, d = nf * 16 + lr;
          attn_out[(b_ * 64 + i) * 256 + head * 32 + d] = (bf16_t)O[mf][nf][r];
        }
  }
}

extern "C" void kernel_launch(void* const* d_in, const int* in_sizes, int n_in,
                              void* d_out, int out_size, void* d_ws, size_t ws_size,
                              hipStream_t stream) {
  const float* x = (const float*)d_in[0];
  const float* n1w = (const float*)d_in[1];
  const float* n1b = (const float*)d_in[2];
  const float* qkv_w = (const float*)d_in[3];
  const float* qkv_b = (const float*)d_in[4];
  const float* rpb = (const float*)d_in[5];
  const float* proj_w = (const float*)d_in[6];
  const float* proj_b = (const float*)d_in[7];
  const float* n2w = (const float*)d_in[8];
  const float* n2b = (const float*)d_in[9];
  const float* fc1_w = (const float*)d_in[10];
  const float* fc1_b = (const float*)d_in[11];
  const float* fc2_w = (const float*)d_in[12];
  const float* fc2_b = (const float*)d_in[13];
  float* out = (float*)d_out;

  char* ws = (char*)d_ws;
  bf16_t* bufA = (bf16_t*)ws;                       // qkv (201MB)
  bf16_t* x1b = (bf16_t*)(ws + 201326592L);         // x1 bf16 (67MB)
  bf16_t* bufB = (bf16_t*)(ws + 268435456L);        // xw / attn_out (67MB)
  bf16_t* wq = (bf16_t*)(ws + 335544320L);          // bf16 weights (1.6MB)
  bf16_t* wp = wq + 196608;
  bf16_t* w1 = wp + 65536;
  bf16_t* w2 = w1 + 262144;

  // all weights -> bf16 in ONE dispatch
  cvt_all_kernel<<<768, 256, 0, stream>>>(qkv_w, proj_w, fc1_w, fc2_w, wq, wp, w1, w2);

  // LN1 + shift + window partition -> xw (bufB)
  ln_kernel<<<32768, 256, 0, stream>>>(x, n1w, n1b, bufB);
  // QKV GEMM -> q/k/v_t (bufA)
  gemm_kernel<0><<<dim3(6, 1024), 256, 0, stream>>>(bufB, wq, qkv_b, 256, bufA, nullptr);
  // window attention -> attn_out (bufB)
  attn_kernel<<<2048, 256, 0, stream>>>(bufA, rpb, bufB);
  // proj + reverse shift + residual(x) -> x1 bf16
  gemm_kernel<1><<<dim3(2, 1024), 256, 0, stream>>>(bufB, wp, proj_b, 256, x1b, x);
  // fused LN2 + FC1 + GeLU + FC2 + residual -> d_out (fp32, sole writer)
  mlp_kernel<<<2048, 512, 0, stream>>>(x1b, out, n2w, n2b, w1, fc1_b, w2, fc2_b);
}